// Round 13
// baseline (1524.669 us; speedup 1.0000x reference)
//
#include <hip/hip_runtime.h>
#include <hip/hip_bf16.h>
#include <stdint.h>

#define DEV __device__ __forceinline__

typedef unsigned short u16;
typedef __attribute__((ext_vector_type(8))) short bf16x8;
typedef __attribute__((ext_vector_type(4))) float f32x4;
typedef __attribute__((ext_vector_type(4))) unsigned short u16x4;

constexpr int H  = 256;
constexpr int R  = 480;
constexpr int RP = 512;   // padded K for the gi GEMM
constexpr int NE = 23000;
constexpr int NT = 8192;
constexpr int TT = 10;

DEV u16 f2b(float f) {
  union { float f; unsigned u; } x; x.f = f;
  unsigned u = x.u;
  return (u16)((u + 0x7fffu + ((u >> 16) & 1u)) >> 16);
}
DEV float b2f(u16 h) {
  union { unsigned u; float f; } x; x.u = ((unsigned)h) << 16;
  return x.f;
}

DEV void gload_lds16(const u16* g, u16* lds) {
  __builtin_amdgcn_global_load_lds(
      (const __attribute__((address_space(1))) unsigned int*)g,
      (__attribute__((address_space(3))) unsigned int*)lds, 16, 0, 0);
}

// ---------------- fused rank-480 precompute + weight prep ------------------
__launch_bounds__(256)
__global__ void stageA_k(const float* __restrict__ r_emb,
                         const float* __restrict__ Wm1, const float* __restrict__ bm1,
                         const float* __restrict__ Wm2, const float* __restrict__ bm2,
                         const float* __restrict__ Wattn, const float* __restrict__ battn,
                         const float* __restrict__ Wih,
                         const float* __restrict__ Wh1, const float* __restrict__ bh1,
                         const float* __restrict__ Wh2, const float* __restrict__ bh2,
                         const float* __restrict__ Whh, const float* __restrict__ bhh,
                         const float* __restrict__ bih, const float* __restrict__ Walign,
                         float* __restrict__ mapped, float* __restrict__ t1,
                         float* __restrict__ Pg, float* __restrict__ G2,
                         u16* __restrict__ MWT, u16* __restrict__ WhhT,
                         u16* __restrict__ WalignT, float* __restrict__ bsum) {
  const int j = threadIdx.x;
  if (blockIdx.x >= 480) {
    const int b = blockIdx.x - 480;
    if (b < 768) {
      WhhT[(size_t)b * 256 + j] = f2b(Whh[(size_t)j * 768 + b]);
    } else if (b < 1024) {
      const int n = b - 768;
      WalignT[(size_t)n * 256 + j] = f2b(Walign[(size_t)j * 256 + n]);
    } else if (b < 1027) {
      const int c = (b - 1024) * 256 + j;
      if (c < 768) bsum[c] = bih[c] + (c < 512 ? bhh[c] : 0.f);
    } else {
      const int row = (b - 1027) * 256 + j;      // 0..767
      if (row < 768) {
        const u16x4 z = {0, 0, 0, 0};
        #pragma unroll
        for (int c = 480; c < 512; c += 4) *(u16x4*)&MWT[(size_t)row * RP + c] = z;
      }
    }
    return;
  }
  __shared__ float re[256], hid[512], mp[256], p1l[256], Pl[256];
  __shared__ float mwl[768], pwl[768];
  __shared__ f32x4 red4[256];
  const int r = blockIdx.x;
  const f32x4 z4 = {0.f, 0.f, 0.f, 0.f};
  re[j] = r_emb[(size_t)r * 256 + j];
  __syncthreads();
  {
    const int q = j & 127, g = j >> 7;
    f32x4 acc = (g == 0) ? *(const f32x4*)&bm1[q * 4] : z4;
    for (int k = g * 128; k < g * 128 + 128; ++k)
      acc += re[k] * *(const f32x4*)&Wm1[(size_t)k * 512 + q * 4];
    red4[j] = acc;
    __syncthreads();
    if (j < 128) *(f32x4*)&hid[j * 4] = red4[j] + red4[j + 128];
    __syncthreads();
  }
  {
    const int q = j & 63, g = j >> 6;
    f32x4 acc = (g == 0) ? *(const f32x4*)&bm2[q * 4] : z4;
    for (int k = g * 128; k < g * 128 + 128; ++k)
      acc += hid[k] * *(const f32x4*)&Wm2[(size_t)k * 256 + q * 4];
    red4[j] = acc;
    __syncthreads();
    if (j < 64) {
      const f32x4 s = red4[j] + red4[j + 64] + red4[j + 128] + red4[j + 192];
      *(f32x4*)&mp[j * 4] = s;
      *(f32x4*)&mapped[(size_t)r * 256 + j * 4] = s;
    }
    __syncthreads();
  }
  {
    const int q = j & 63, g = j >> 6;
    f32x4 acc = (g == 0) ? *(const f32x4*)&battn[q * 4] : z4;
    for (int k = g * 64; k < g * 64 + 64; ++k)
      acc += mp[k] * *(const f32x4*)&Wattn[(size_t)k * 256 + q * 4];
    red4[j] = acc;
    __syncthreads();
    if (j < 64)
      *(f32x4*)&t1[(size_t)r * 256 + j * 4] =
          red4[j] + red4[j + 64] + red4[j + 128] + red4[j + 192];
    __syncthreads();
  }
  if (j < 192) {
    f32x4 acc = z4;
    for (int k = 0; k < 256; ++k)
      acc += mp[k] * *(const f32x4*)&Wih[(size_t)k * 768 + j * 4];
    *(f32x4*)&mwl[j * 4] = acc;
    #pragma unroll
    for (int c = 0; c < 4; ++c) MWT[(size_t)(j * 4 + c) * RP + r] = f2b(acc[c]);
  }
  __syncthreads();
  {
    const int q = j & 63, g = j >> 6;
    f32x4 acc = (g == 0) ? *(const f32x4*)&bh1[q * 4] : z4;
    for (int k = g * 64; k < g * 64 + 64; ++k)
      acc += mp[k] * *(const f32x4*)&Wh1[(size_t)k * 256 + q * 4];
    red4[j] = acc;
    __syncthreads();
    if (j < 64) *(f32x4*)&p1l[j * 4] = red4[j] + red4[j + 64] + red4[j + 128] + red4[j + 192];
    __syncthreads();
  }
  {
    const int q = j & 63, g = j >> 6;
    f32x4 acc = (g == 0) ? *(const f32x4*)&bh2[q * 4] : z4;
    for (int k = g * 64; k < g * 64 + 64; ++k)
      acc += p1l[k] * *(const f32x4*)&Wh2[(size_t)k * 256 + q * 4];
    red4[j] = acc;
    __syncthreads();
    if (j < 64) {
      f32x4 s = red4[j] + red4[j + 64] + red4[j + 128] + red4[j + 192];
      const f32x4 mv = *(const f32x4*)&mp[j * 4];
      #pragma unroll
      for (int c = 0; c < 4; ++c) s[c] = 0.1f * s[c] + mv[c];
      *(f32x4*)&Pl[j * 4] = s;
      *(f32x4*)&Pg[(size_t)r * 256 + j * 4] = s;
    }
    __syncthreads();
  }
  if (j < 192) {
    f32x4 acc = *(const f32x4*)&bhh[j * 4];
    for (int k = 0; k < 256; ++k)
      acc += Pl[k] * *(const f32x4*)&Whh[(size_t)k * 768 + j * 4];
    *(f32x4*)&pwl[j * 4] = acc;
  }
  __syncthreads();
  {
    const float rg = 1.f / (1.f + __expf(-(mwl[j] + bih[j] + pwl[j])));
    const float zg = 1.f / (1.f + __expf(-(mwl[j + 256] + bih[j + 256] + pwl[j + 256])));
    const float ng = tanhf(mwl[j + 512] + bih[j + 512] + rg * pwl[j + 512]);
    G2[(size_t)r * 256 + j] = (1.f - zg) * ng + zg * Pl[j];
  }
}

// ---------------- B480 = t1 @ mapped^T (exact f32, f32x4 dot) --------------
__global__ void sgemm_bt_k(const float* __restrict__ A, const float* __restrict__ W,
                           float* __restrict__ C, int M, int N, int K) {
  const int idx = blockIdx.x * 256 + threadIdx.x;
  if (idx >= M * N) return;
  const int i = idx / N, j = idx % N;
  const f32x4* a4 = (const f32x4*)(A + (size_t)i * K);
  const f32x4* w4 = (const f32x4*)(W + (size_t)j * K);
  f32x4 acc = {0.f, 0.f, 0.f, 0.f};
  for (int k = 0; k < K / 4; ++k) acc += a4[k] * w4[k];
  C[idx] = acc[0] + acc[1] + acc[2] + acc[3];
}

// ---------------- masked softmax for all steps (f32x4 loads) ---------------
__global__ void softmax_all_k(const float* __restrict__ part, const float* __restrict__ B480,
                              const int* __restrict__ rel_idx, u16* __restrict__ attn) {
  const int task = blockIdx.x * 4 + (threadIdx.x >> 6);
  const int lane = threadIdx.x & 63;
  const int tt = task >> 13;            // /NT
  const int i  = task & (NT - 1);
  const float* cur = part + (size_t)i * (TT * R) + (size_t)tt * R;
  const float* b = B480 + (size_t)rel_idx[i] * R;
  f32x4 v[2];
  float m = -3e38f;
  const bool act1 = lane < 56;
  #pragma unroll
  for (int jj = 0; jj < 2; ++jj) {
    const int r0 = jj * 256 + lane * 4;
    f32x4 val = {-1e9f, -1e9f, -1e9f, -1e9f};
    if (jj == 0 || act1) {
      const f32x4 c4 = *(const f32x4*)&cur[r0];
      const f32x4 b4 = *(const f32x4*)&b[r0];
      #pragma unroll
      for (int x = 0; x < 4; ++x) {
        val[x] = (c4[x] == 0.f) ? -1e9f : c4[x] * b4[x];
        m = fmaxf(m, val[x]);
      }
    }
    v[jj] = val;
  }
  #pragma unroll
  for (int o = 32; o; o >>= 1) m = fmaxf(m, __shfl_xor(m, o));
  float s = 0.f;
  #pragma unroll
  for (int jj = 0; jj < 2; ++jj) {
    if (jj == 0 || act1) {
      #pragma unroll
      for (int x = 0; x < 4; ++x) { v[jj][x] = __expf(v[jj][x] - m); s += v[jj][x]; }
    }
  }
  #pragma unroll
  for (int o = 32; o; o >>= 1) s += __shfl_xor(s, o);
  const float inv = 1.f / s;
  u16* arow = attn + (size_t)task * RP;
  #pragma unroll
  for (int jj = 0; jj < 2; ++jj) {
    const int r0 = jj * 256 + lane * 4;
    u16x4 o = {0, 0, 0, 0};
    if (jj == 0 || act1) {
      #pragma unroll
      for (int x = 0; x < 4; ++x) o[x] = f2b(v[jj][x] * inv);
    }
    *(u16x4*)&arow[r0] = o;
  }
}

// ---------------- single-launch 10-step scan -------------------------------
__launch_bounds__(256)
__global__ void scan_k(const u16* __restrict__ WhhT, const float* __restrict__ bhh,
                       const u16* __restrict__ gi_all, float* __restrict__ hbuf) {
  __shared__ __align__(16) u16 As[32 * 256];
  __shared__ __align__(16) u16 Bs[2][192 * 64];
  const int tid = threadIdx.x;
  const int lane = tid & 63;
  const int wv = tid >> 6;
  const int rf = wv >> 1;
  const int ch = wv & 1;
  const int fr = lane & 15;
  const int fq = lane >> 4;
  const int row_l = rf * 16 + fr;
  const int grow = blockIdx.x * 32 + row_l;
  const int sw = (fr & 7) * 8;

  auto stageB = [&](int buf, int cg, int k0) {
    #pragma unroll
    for (int it = 0; it < 6; ++it) {
      const int c = it * 256 + tid;
      const int vr = c >> 3, s = c & 7;
      const int vcol = ((vr >> 6) * 256) + cg * 64 + (vr & 63);
      gload_lds16(WhhT + (size_t)vcol * 256 + k0 + ((s ^ (vr & 7)) * 8),
                  &Bs[buf][(it * 256 + wv * 64) * 8]);
    }
  };

  float hreg[4][2][4];
  #pragma unroll
  for (int cg = 0; cg < 4; ++cg)
    #pragma unroll
    for (int nn = 0; nn < 2; ++nn)
      #pragma unroll
      for (int j = 0; j < 4; ++j) hreg[cg][nn][j] = 0.f;

  for (int t = 0; t < TT; ++t) {
    const u16* gi = gi_all + (size_t)t * NT * 768;
    #pragma unroll
    for (int cg = 0; cg < 4; ++cg) {
      f32x4 acc[6] = {};
      u16x4 gv[3][2];
      #pragma unroll
      for (int nn = 0; nn < 2; ++nn) {
        const int c = cg * 64 + ch * 32 + nn * 16 + fq * 4;
        const size_t gb = (size_t)grow * 768 + c;
        gv[0][nn] = *(const u16x4*)&gi[gb];
        gv[1][nn] = *(const u16x4*)&gi[gb + 256];
        gv[2][nn] = *(const u16x4*)&gi[gb + 512];
      }
      if (t > 0) {
        stageB(0, cg, 0);
        #pragma unroll
        for (int ki = 0; ki < 4; ++ki) {
          const int cb = ki & 1;
          if (ki < 3) {
            stageB(cb ^ 1, cg, (ki + 1) * 64);
            asm volatile("s_waitcnt vmcnt(6)" ::: "memory");
          } else {
            asm volatile("s_waitcnt vmcnt(0)" ::: "memory");
          }
          __builtin_amdgcn_sched_barrier(0);
          __builtin_amdgcn_s_barrier();
          #pragma unroll
          for (int kk = 0; kk < 2; ++kk) {
            const int ko = (ki * 64 + kk * 32 + fq * 8) ^ sw;
            const bf16x8 a = *(const bf16x8*)&As[row_l * 256 + ko];
            const int bo = (kk * 32 + fq * 8) ^ sw;
            #pragma unroll
            for (int g = 0; g < 3; ++g)
              #pragma unroll
              for (int nn = 0; nn < 2; ++nn) {
                const int vr = g * 64 + ch * 32 + nn * 16 + fr;
                const bf16x8 b = *(const bf16x8*)&Bs[cb][vr * 64 + bo];
                acc[g * 2 + nn] =
                    __builtin_amdgcn_mfma_f32_16x16x32_bf16(b, a, acc[g * 2 + nn], 0, 0, 0);
              }
          }
          __builtin_amdgcn_s_barrier();
        }
      }
      #pragma unroll
      for (int nn = 0; nn < 2; ++nn) {
        const int c = cg * 64 + ch * 32 + nn * 16 + fq * 4;
        const f32x4 bn = *(const f32x4*)&bhh[512 + c];
        #pragma unroll
        for (int j = 0; j < 4; ++j) {
          const float rg = 1.f / (1.f + __expf(-(b2f(gv[0][nn][j]) + acc[nn][j])));
          const float zg = 1.f / (1.f + __expf(-(b2f(gv[1][nn][j]) + acc[2 + nn][j])));
          const float ng = tanhf(b2f(gv[2][nn][j]) + rg * (acc[4 + nn][j] + bn[j]));
          hreg[cg][nn][j] = (1.f - zg) * ng + zg * hreg[cg][nn][j];
        }
      }
    }
    #pragma unroll
    for (int cg = 0; cg < 4; ++cg)
      #pragma unroll
      for (int nn = 0; nn < 2; ++nn) {
        const int c = cg * 64 + ch * 32 + nn * 16 + fq * 4;
        u16x4 o;
        #pragma unroll
        for (int j = 0; j < 4; ++j) o[j] = f2b(hreg[cg][nn][j]);
        *(u16x4*)&As[row_l * 256 + (c ^ sw)] = o;
        if (t == TT - 1) {
          f32x4 hv;
          #pragma unroll
          for (int j = 0; j < 4; ++j) hv[j] = hreg[cg][nn][j];
          *(f32x4*)&hbuf[(size_t)grow * 256 + c] = hv;
        }
      }
    __syncthreads();
  }
}

// ---------------- gathers / converts (vectorized) --------------------------
__global__ void gather_sub_k(const float* __restrict__ pre, const int* __restrict__ sub,
                             u16* __restrict__ sb) {
  const int q = blockIdx.x * 256 + threadIdx.x;
  const int i = q >> 6, c = (q & 63) * 4;
  const f32x4 v = *(const f32x4*)&pre[(size_t)sub[i] * H + c];
  u16x4 o;
  #pragma unroll
  for (int j = 0; j < 4; ++j) o[j] = f2b(v[j]);
  *(u16x4*)&sb[(size_t)q * 4] = o;
}
__global__ void cvt_pre_k(const float* __restrict__ pre, u16* __restrict__ pb) {
  const int q = blockIdx.x * 256 + threadIdx.x;
  const f32x4 v = *(const f32x4*)&pre[(size_t)q * 4];
  u16x4 o;
  #pragma unroll
  for (int j = 0; j < 4; ++j) o[j] = f2b(v[j]);
  *(u16x4*)&pb[(size_t)q * 4] = o;
}

// ---------------- final scalar reduction -----------------------------------
__global__ void finalize_k(const float* __restrict__ mp, const float* __restrict__ sp,
                           float* __restrict__ out) {
  const int tid = threadIdx.x;
  float s1 = 0.f, s2 = 0.f;
  for (int i = tid; i < 128; i += 256) s1 += mp[i];
  for (int i = tid; i < 3072; i += 256) s2 += sp[i];
  #pragma unroll
  for (int o = 32; o; o >>= 1) {
    s1 += __shfl_down(s1, o); s2 += __shfl_down(s2, o);
  }
  __shared__ float r1[4], r2[4];
  if ((tid & 63) == 0) { r1[tid >> 6] = s1; r2[tid >> 6] = s2; }
  __syncthreads();
  if (tid == 0) {
    const float a = r1[0] + r1[1] + r1[2] + r1[3];
    const float b = r2[0] + r2[1] + r2[2] + r2[3];
    out[0] = a / 2097152.f;
    out[1] = b / 188416000.f;
  }
}

// ---------------- 128-tile bf16 MFMA GEMM (MODE 0 / 2) ---------------------
template <int MODE>
__launch_bounds__(256)
__global__ void gemm_k(const u16* __restrict__ A, const u16* __restrict__ Bt,
                       const float* __restrict__ bias,
                       float* __restrict__ Cf, u16* __restrict__ Cb,
                       int M, int N, int K,
                       float* __restrict__ out2, float* __restrict__ part,
                       const int* __restrict__ idxv, const float* __restrict__ Pf,
                       const float* __restrict__ G2f, const float* __restrict__ hf) {
  __shared__ __align__(16) u16 As[128 * 64];
  __shared__ __align__(16) u16 Bs[128 * 64];
  __shared__ float red[4];
  const int tid = threadIdx.x;
  const int lane = tid & 63;
  const int wv = tid >> 6;
  const int nbx = gridDim.x;
  int flat = blockIdx.y * nbx + blockIdx.x;
  const int nwg = nbx * gridDim.y;
  if ((nwg & 7) == 0) flat = (flat & 7) * (nwg >> 3) + (flat >> 3);
  const int bx = flat % nbx;
  const int by = flat / nbx;
  const int m0 = by * 128;
  const int n0 = bx * 128;
  const int wm = (wv >> 1) * 64;
  const int wn = (wv & 1) * 64;
  const int fr = lane & 15;
  const int fq = lane >> 4;
  const int sw = (lane & 7) * 8;
  f32x4 acc[4][4] = {};

  const int nsteps = K >> 6;
  for (int kt = 0; kt < nsteps; ++kt) {
    const int k0 = kt * 64;
    if (kt > 0) __syncthreads();
    #pragma unroll
    for (int it = 0; it < 4; ++it) {
      const int c = it * 256 + tid;
      const int row = c >> 3, s = c & 7;
      const int sc = (s ^ (row & 7)) * 8;
      int gr = m0 + row; gr = gr < M ? gr : M - 1;
      gload_lds16(A + (size_t)gr * K + k0 + sc, &As[(it * 256 + wv * 64) * 8]);
      int nr = n0 + row; nr = nr < N ? nr : N - 1;
      gload_lds16(Bt + (size_t)nr * K + k0 + sc, &Bs[(it * 256 + wv * 64) * 8]);
    }
    asm volatile("s_waitcnt vmcnt(0)" ::: "memory");
    __builtin_amdgcn_sched_barrier(0);
    __builtin_amdgcn_s_barrier();
    #pragma unroll
    for (int kk = 0; kk < 2; ++kk) {
      const int ko = (kk * 32 + fq * 8) ^ sw;
      bf16x8 a[4], b[4];
      #pragma unroll
      for (int mi = 0; mi < 4; ++mi)
        a[mi] = *(const bf16x8*)&As[(wm + mi * 16 + fr) * 64 + ko];
      #pragma unroll
      for (int ni = 0; ni < 4; ++ni)
        b[ni] = *(const bf16x8*)&Bs[(wn + ni * 16 + fr) * 64 + ko];
      #pragma unroll
      for (int mi = 0; mi < 4; ++mi)
        #pragma unroll
        for (int ni = 0; ni < 4; ++ni)
          acc[mi][ni] = __builtin_amdgcn_mfma_f32_16x16x32_bf16(b[ni], a[mi], acc[mi][ni], 0, 0, 0);
    }
  }

  float local = 0.f;
  #pragma unroll
  for (int mi = 0; mi < 4; ++mi) {
    const int rowm = m0 + wm + mi * 16 + fr;
    int iv = 0;
    if (MODE == 2) iv = idxv[rowm < M ? rowm : M - 1];
    #pragma unroll
    for (int ni = 0; ni < 4; ++ni) {
      const int col = n0 + wn + ni * 16 + fq * 4;
      if (rowm < M && col < N) {
        f32x4 v = acc[mi][ni];
        if (MODE == 0) {
          if (bias != nullptr) {
            const f32x4 bv = *(const f32x4*)&bias[col];
            #pragma unroll
            for (int j = 0; j < 4; ++j) v[j] += bv[j];
          }
          if (Cf) *(f32x4*)&Cf[(size_t)rowm * N + col] = v;
          if (Cb) {
            u16x4 o;
            #pragma unroll
            for (int j = 0; j < 4; ++j) o[j] = f2b(v[j]);
            *(u16x4*)&Cb[(size_t)rowm * N + col] = o;
          }
        } else {
          const f32x4 bv = *(const f32x4*)&bias[col];
          const f32x4 Pv = *(const f32x4*)&Pf[(size_t)iv * H + col];
          const f32x4 Gv = *(const f32x4*)&G2f[(size_t)iv * H + col];
          const f32x4 hv = *(const f32x4*)&hf[(size_t)rowm * H + col];
          u16x4 o;
          #pragma unroll
          for (int j = 0; j < 4; ++j) {
            const float d = Pv[j] - hv[j];
            local += d * d;
            o[j] = f2b((v[j] + bv[j]) * Gv[j]);
          }
          *(u16x4*)&Cb[(size_t)rowm * N + col] = o;
        }
      }
    }
  }
  if (MODE == 2) {
    #pragma unroll
    for (int o = 32; o; o >>= 1) local += __shfl_down(local, o);
    if (lane == 0) red[wv] = local;
    __syncthreads();
    if (tid == 0) part[blockIdx.y * gridDim.x + blockIdx.x] = red[0] + red[1] + red[2] + red[3];
  }
}

// ---------------- 256-tile bf16 MFMA GEMM, BK=64 single-buffer -------------
// MODE 0: Cb = bf16(A@B + bias)   (gi GEMM; old %8 swizzle)
// MODE 1: sigmoid -> out2 (NONTEMPORAL), (softplus - pos) partials -> part.
//   XCD-column-affine mapping: grid (96,32); xcd = flat&7 owns a 12-wide
//   column slice (alT slice 1.57 MB -> per-XCD-L2 resident). nt stores keep
//   out2's 754 MB stream from evicting it. Idle blocks (bx>=90) zero their
//   part slot and exit (before any barrier).
template <int MODE>
__launch_bounds__(512)
__global__ void gemm256_k(const u16* __restrict__ A, const u16* __restrict__ Bt,
                          const float* __restrict__ bias, u16* __restrict__ Cb,
                          int M, int N, int K,
                          float* __restrict__ out2, float* __restrict__ part,
                          const int* __restrict__ idxv) {
  __shared__ __align__(16) u16 As[256 * 64];
  __shared__ __align__(16) u16 Bs[256 * 64];
  __shared__ float red[8];
  const int tid = threadIdx.x;
  const int lane = tid & 63;
  const int wv = tid >> 6;
  int bx, by, pslot;
  if (MODE == 1) {
    const int flat = blockIdx.y * 96 + blockIdx.x;   // gridDim.x == 96
    pslot = flat;
    const int xcd = flat & 7;
    const int i = flat >> 3;                          // 0..383
    bx = xcd * 12 + (i % 12);
    by = i / 12;                                      // 0..31
    if (bx >= 90) {                                   // 23040-col pad region
      if (tid == 0) part[pslot] = 0.f;
      return;
    }
  } else {
    const int nbx = gridDim.x;
    int flat = blockIdx.y * nbx + blockIdx.x;
    const int nwg = nbx * gridDim.y;
    if ((nwg & 7) == 0) flat = (flat & 7) * (nwg >> 3) + (flat >> 3);
    bx = flat % nbx;
    by = flat / nbx;
    pslot = 0;
  }
  const int m0 = by * 256;
  const int n0 = bx * 256;
  const int wm = (wv >> 2) * 128;      // 2 M-groups of 128
  const int wn = (wv & 3) * 64;        // 4 N-groups of 64
  const int fr = lane & 15;
  const int fq = lane >> 4;
  const int sw = (lane & 7) * 8;
  f32x4 acc[8][4] = {};

  const int nsteps = K >> 6;
  for (int kt = 0; kt < nsteps; ++kt) {
    const int k0 = kt * 64;
    if (kt > 0) __syncthreads();        // WAR: all waves done reading LDS
    #pragma unroll
    for (int it = 0; it < 4; ++it) {
      const int c = it * 512 + tid;     // 2048 16B chunks per matrix
      const int row = c >> 3, s = c & 7;
      const int sc = (s ^ (row & 7)) * 8;
      int gr = m0 + row; gr = gr < M ? gr : M - 1;
      gload_lds16(A + (size_t)gr * K + k0 + sc, &As[(it * 512 + wv * 64) * 8]);
      int nr = n0 + row; nr = nr < N ? nr : N - 1;
      gload_lds16(Bt + (size_t)nr * K + k0 + sc, &Bs[(it * 512 + wv * 64) * 8]);
    }
    asm volatile("s_waitcnt vmcnt(0)" ::: "memory");
    __builtin_amdgcn_sched_barrier(0);
    __builtin_amdgcn_s_barrier();
    #pragma unroll
    for (int kk = 0; kk < 2; ++kk) {
      const int ko = (kk * 32 + fq * 8) ^ sw;
      bf16x8 a[8], b[4];
      #pragma unroll
      for (int mi = 0; mi < 8; ++mi)
        a[mi] = *(const bf16x8*)&As[(wm + mi * 16 + fr) * 64 + ko];
      #pragma unroll
      for (int ni = 0; ni < 4; ++ni)
        b[ni] = *(const bf16x8*)&Bs[(wn + ni * 16 + fr) * 64 + ko];
      #pragma unroll
      for (int mi = 0; mi < 8; ++mi)
        #pragma unroll
        for (int ni = 0; ni < 4; ++ni)
          acc[mi][ni] = __builtin_amdgcn_mfma_f32_16x16x32_bf16(b[ni], a[mi], acc[mi][ni], 0, 0, 0);
    }
  }

  float local = 0.f;
  #pragma unroll
  for (int mi = 0; mi < 8; ++mi) {
    const int rowm = m0 + wm + mi * 16 + fr;
    int iv = 0;
    if (MODE == 1) iv = idxv[rowm < M ? rowm : M - 1];
    #pragma unroll
    for (int ni = 0; ni < 4; ++ni) {
      const int col = n0 + wn + ni * 16 + fq * 4;
      if (rowm < M && col < N) {
        const f32x4 v = acc[mi][ni];
        if (MODE == 0) {
          const f32x4 bv = *(const f32x4*)&bias[col];
          u16x4 o;
          #pragma unroll
          for (int j = 0; j < 4; ++j) o[j] = f2b(v[j] + bv[j]);
          *(u16x4*)&Cb[(size_t)rowm * N + col] = o;
        } else {
          f32x4 sg;
          #pragma unroll
          for (int j = 0; j < 4; ++j) {
            const float s = v[j];
            const float sig = 1.f / (1.f + __expf(-s));
            sg[j] = sig;
            const float om = 1.f - sig;
            local += (om > 0.f) ? -__logf(om) : s;     // softplus(s)
            if (col + j == iv) local -= s;             // pos fold
          }
          __builtin_nontemporal_store(sg, (f32x4*)&out2[(size_t)rowm * N + col]);
        }
      }
    }
  }
  if (MODE == 1) {
    #pragma unroll
    for (int o = 32; o; o >>= 1) local += __shfl_down(local, o);
    if (lane == 0) red[wv] = local;
    __syncthreads();
    if (tid == 0) {
      float s = 0.f;
      #pragma unroll
      for (int x = 0; x < 8; ++x) s += red[x];
      part[pslot] = s;
    }
  }
}

extern "C" void kernel_launch(void* const* d_in, const int* in_sizes, int n_in,
                              void* d_out, int out_size, void* d_ws, size_t ws_size,
                              hipStream_t stream) {
  const float* pre_emb = (const float*)d_in[0];
  const float* r_emb   = (const float*)d_in[1];
  const float* part_e  = (const float*)d_in[2];
  const int*   sub_idx = (const int*)d_in[3];
  const int*   rel_idx = (const int*)d_in[4];
  const int*   obj_idx = (const int*)d_in[5];
  const float* Wm1 = (const float*)d_in[7];  const float* bm1 = (const float*)d_in[8];
  const float* Wm2 = (const float*)d_in[9];  const float* bm2 = (const float*)d_in[10];
  const float* Wattn = (const float*)d_in[11]; const float* battn = (const float*)d_in[12];
  const float* Wh1 = (const float*)d_in[13]; const float* bh1 = (const float*)d_in[14];
  const float* Wh2 = (const float*)d_in[15]; const float* bh2 = (const float*)d_in[16];
  const float* Walign = (const float*)d_in[17]; const float* balign = (const float*)d_in[18];
  const float* Wih = (const float*)d_in[19]; const float* Whh = (const float*)d_in[20];
  const float* bih = (const float*)d_in[21]; const float* bhh = (const float*)d_in[22];
  float* out = (float*)d_out;

  char* w = (char*)d_ws;
  size_t off = 0;
  auto alloc = [&](size_t bytes) -> void* {
    off = (off + 255) & ~(size_t)255;
    void* p = w + off;
    off += bytes;
    return p;
  };
  float* mapped = (float*)alloc((size_t)R * H * 4);
  float* t1     = (float*)alloc((size_t)R * H * 4);
  float* B480   = (float*)alloc((size_t)R * R * 4);
  float* P      = (float*)alloc((size_t)R * H * 4);
  float* G2     = (float*)alloc((size_t)R * H * 4);
  u16* MWT      = (u16*)alloc((size_t)768 * RP * 2);
  u16* WhhT     = (u16*)alloc((size_t)768 * H * 2);
  u16* WalignT  = (u16*)alloc((size_t)H * H * 2);
  float* bsum   = (float*)alloc(768 * 4);
  float* hbuf   = (float*)alloc((size_t)NT * H * 4);
  u16* lhs_b    = (u16*)alloc((size_t)NT * H * 2);
  u16* sub_b    = (u16*)alloc((size_t)NT * H * 2);
  u16* pre_b    = (u16*)alloc((size_t)NE * H * 2);
  u16* alT      = (u16*)alloc((size_t)NE * H * 2);
  float* mpart  = (float*)alloc(128 * 4);
  float* spart  = (float*)alloc(3072 * 4);
  u16* attn_all = (u16*)alloc((size_t)TT * NT * RP * 2);
  u16* gi_all   = (u16*)alloc((size_t)TT * NT * 768 * 2);
  if (off > ws_size) return;  // workspace insufficient; fail visibly

  // rank-480 precompute + weight prep + MWT pad (one launch)
  stageA_k<<<480 + 1030, 256, 0, stream>>>(
      r_emb, Wm1, bm1, Wm2, bm2, Wattn, battn, Wih, Wh1, bh1, Wh2, bh2,
      Whh, bhh, bih, Walign, mapped, t1, P, G2, MWT, WhhT, WalignT, bsum);
  sgemm_bt_k<<<(R * R + 255) / 256, 256, 0, stream>>>(t1, mapped, B480, R, R, H);

  // all-step softmax + batched gi GEMM (256-tile) + single-launch scan
  softmax_all_k<<<TT * (NT / 4), 256, 0, stream>>>(part_e, B480, rel_idx, attn_all);
  gemm256_k<0><<<dim3(3, TT * (NT / 256)), 512, 0, stream>>>(
      attn_all, MWT, bsum, gi_all, TT * NT, 768, RP, nullptr, nullptr, nullptr);
  scan_k<<<NT / 32, 256, 0, stream>>>(WhhT, bhh, gi_all, hbuf);

  // sub gather + fused (asub GEMM + lhs + match partials)
  gather_sub_k<<<NT / 4, 256, 0, stream>>>(pre_emb, sub_idx, sub_b);
  gemm_k<2><<<dim3(2, 64), 256, 0, stream>>>(
      sub_b, WalignT, balign, nullptr, lhs_b, NT, H, H,
      nullptr, mpart, rel_idx, P, G2, hbuf);

  // aligned entity table
  cvt_pre_k<<<NE / 4, 256, 0, stream>>>(pre_emb, pre_b);
  gemm_k<0><<<dim3(2, 180), 256, 0, stream>>>(
      pre_b, WalignT, balign, nullptr, alT, NE, H, H,
      nullptr, nullptr, nullptr, nullptr, nullptr, nullptr);

  // final score GEMM: XCD-column-affine grid (96,32), nt stores
  gemm256_k<1><<<dim3(96, 32), 512, 0, stream>>>(
      lhs_b, alT, nullptr, nullptr, NT, NE, H, out + 2, spart, obj_idx);

  // final scalars
  finalize_k<<<1, 256, 0, stream>>>(mpart, spart, out);
}

// Round 14
// 1061.078 us; speedup vs baseline: 1.4369x; 1.4369x over previous
//
#include <hip/hip_runtime.h>
#include <hip/hip_bf16.h>
#include <stdint.h>

#define DEV __device__ __forceinline__

typedef unsigned short u16;
typedef __attribute__((ext_vector_type(8))) short bf16x8;
typedef __attribute__((ext_vector_type(4))) float f32x4;
typedef __attribute__((ext_vector_type(4))) unsigned short u16x4;

constexpr int H  = 256;
constexpr int R  = 480;
constexpr int RP = 512;   // padded K for the gi GEMM
constexpr int NE = 23000;
constexpr int NT = 8192;
constexpr int TT = 10;

DEV u16 f2b(float f) {
  union { float f; unsigned u; } x; x.f = f;
  unsigned u = x.u;
  return (u16)((u + 0x7fffu + ((u >> 16) & 1u)) >> 16);
}
DEV float b2f(u16 h) {
  union { unsigned u; float f; } x; x.u = ((unsigned)h) << 16;
  return x.f;
}

DEV void gload_lds16(const u16* g, u16* lds) {
  __builtin_amdgcn_global_load_lds(
      (const __attribute__((address_space(1))) unsigned int*)g,
      (__attribute__((address_space(3))) unsigned int*)lds, 16, 0, 0);
}

// ---------------- fused rank-480 precompute + weight prep ------------------
__launch_bounds__(256)
__global__ void stageA_k(const float* __restrict__ r_emb,
                         const float* __restrict__ Wm1, const float* __restrict__ bm1,
                         const float* __restrict__ Wm2, const float* __restrict__ bm2,
                         const float* __restrict__ Wattn, const float* __restrict__ battn,
                         const float* __restrict__ Wih,
                         const float* __restrict__ Wh1, const float* __restrict__ bh1,
                         const float* __restrict__ Wh2, const float* __restrict__ bh2,
                         const float* __restrict__ Whh, const float* __restrict__ bhh,
                         const float* __restrict__ bih, const float* __restrict__ Walign,
                         float* __restrict__ mapped, float* __restrict__ t1,
                         float* __restrict__ Pg, float* __restrict__ G2,
                         u16* __restrict__ MWT, u16* __restrict__ WhhT,
                         u16* __restrict__ WalignT, float* __restrict__ bsum) {
  const int j = threadIdx.x;
  if (blockIdx.x >= 480) {
    const int b = blockIdx.x - 480;
    if (b < 768) {
      WhhT[(size_t)b * 256 + j] = f2b(Whh[(size_t)j * 768 + b]);
    } else if (b < 1024) {
      const int n = b - 768;
      WalignT[(size_t)n * 256 + j] = f2b(Walign[(size_t)j * 256 + n]);
    } else if (b < 1027) {
      const int c = (b - 1024) * 256 + j;
      if (c < 768) bsum[c] = bih[c] + (c < 512 ? bhh[c] : 0.f);
    } else {
      const int row = (b - 1027) * 256 + j;      // 0..767
      if (row < 768) {
        const u16x4 z = {0, 0, 0, 0};
        #pragma unroll
        for (int c = 480; c < 512; c += 4) *(u16x4*)&MWT[(size_t)row * RP + c] = z;
      }
    }
    return;
  }
  __shared__ float re[256], hid[512], mp[256], p1l[256], Pl[256];
  __shared__ float mwl[768], pwl[768];
  __shared__ f32x4 red4[256];
  const int r = blockIdx.x;
  const f32x4 z4 = {0.f, 0.f, 0.f, 0.f};
  re[j] = r_emb[(size_t)r * 256 + j];
  __syncthreads();
  {
    const int q = j & 127, g = j >> 7;
    f32x4 acc = (g == 0) ? *(const f32x4*)&bm1[q * 4] : z4;
    for (int k = g * 128; k < g * 128 + 128; ++k)
      acc += re[k] * *(const f32x4*)&Wm1[(size_t)k * 512 + q * 4];
    red4[j] = acc;
    __syncthreads();
    if (j < 128) *(f32x4*)&hid[j * 4] = red4[j] + red4[j + 128];
    __syncthreads();
  }
  {
    const int q = j & 63, g = j >> 6;
    f32x4 acc = (g == 0) ? *(const f32x4*)&bm2[q * 4] : z4;
    for (int k = g * 128; k < g * 128 + 128; ++k)
      acc += hid[k] * *(const f32x4*)&Wm2[(size_t)k * 256 + q * 4];
    red4[j] = acc;
    __syncthreads();
    if (j < 64) {
      const f32x4 s = red4[j] + red4[j + 64] + red4[j + 128] + red4[j + 192];
      *(f32x4*)&mp[j * 4] = s;
      *(f32x4*)&mapped[(size_t)r * 256 + j * 4] = s;
    }
    __syncthreads();
  }
  {
    const int q = j & 63, g = j >> 6;
    f32x4 acc = (g == 0) ? *(const f32x4*)&battn[q * 4] : z4;
    for (int k = g * 64; k < g * 64 + 64; ++k)
      acc += mp[k] * *(const f32x4*)&Wattn[(size_t)k * 256 + q * 4];
    red4[j] = acc;
    __syncthreads();
    if (j < 64)
      *(f32x4*)&t1[(size_t)r * 256 + j * 4] =
          red4[j] + red4[j + 64] + red4[j + 128] + red4[j + 192];
    __syncthreads();
  }
  if (j < 192) {
    f32x4 acc = z4;
    for (int k = 0; k < 256; ++k)
      acc += mp[k] * *(const f32x4*)&Wih[(size_t)k * 768 + j * 4];
    *(f32x4*)&mwl[j * 4] = acc;
    #pragma unroll
    for (int c = 0; c < 4; ++c) MWT[(size_t)(j * 4 + c) * RP + r] = f2b(acc[c]);
  }
  __syncthreads();
  {
    const int q = j & 63, g = j >> 6;
    f32x4 acc = (g == 0) ? *(const f32x4*)&bh1[q * 4] : z4;
    for (int k = g * 64; k < g * 64 + 64; ++k)
      acc += mp[k] * *(const f32x4*)&Wh1[(size_t)k * 256 + q * 4];
    red4[j] = acc;
    __syncthreads();
    if (j < 64) *(f32x4*)&p1l[j * 4] = red4[j] + red4[j + 64] + red4[j + 128] + red4[j + 192];
    __syncthreads();
  }
  {
    const int q = j & 63, g = j >> 6;
    f32x4 acc = (g == 0) ? *(const f32x4*)&bh2[q * 4] : z4;
    for (int k = g * 64; k < g * 64 + 64; ++k)
      acc += p1l[k] * *(const f32x4*)&Wh2[(size_t)k * 256 + q * 4];
    red4[j] = acc;
    __syncthreads();
    if (j < 64) {
      f32x4 s = red4[j] + red4[j + 64] + red4[j + 128] + red4[j + 192];
      const f32x4 mv = *(const f32x4*)&mp[j * 4];
      #pragma unroll
      for (int c = 0; c < 4; ++c) s[c] = 0.1f * s[c] + mv[c];
      *(f32x4*)&Pl[j * 4] = s;
      *(f32x4*)&Pg[(size_t)r * 256 + j * 4] = s;
    }
    __syncthreads();
  }
  if (j < 192) {
    f32x4 acc = *(const f32x4*)&bhh[j * 4];
    for (int k = 0; k < 256; ++k)
      acc += Pl[k] * *(const f32x4*)&Whh[(size_t)k * 768 + j * 4];
    *(f32x4*)&pwl[j * 4] = acc;
  }
  __syncthreads();
  {
    const float rg = 1.f / (1.f + __expf(-(mwl[j] + bih[j] + pwl[j])));
    const float zg = 1.f / (1.f + __expf(-(mwl[j + 256] + bih[j + 256] + pwl[j + 256])));
    const float ng = tanhf(mwl[j + 512] + bih[j + 512] + rg * pwl[j + 512]);
    G2[(size_t)r * 256 + j] = (1.f - zg) * ng + zg * Pl[j];
  }
}

// ---------------- B480 = t1 @ mapped^T (exact f32, f32x4 dot) --------------
__global__ void sgemm_bt_k(const float* __restrict__ A, const float* __restrict__ W,
                           float* __restrict__ C, int M, int N, int K) {
  const int idx = blockIdx.x * 256 + threadIdx.x;
  if (idx >= M * N) return;
  const int i = idx / N, j = idx % N;
  const f32x4* a4 = (const f32x4*)(A + (size_t)i * K);
  const f32x4* w4 = (const f32x4*)(W + (size_t)j * K);
  f32x4 acc = {0.f, 0.f, 0.f, 0.f};
  for (int k = 0; k < K / 4; ++k) acc += a4[k] * w4[k];
  C[idx] = acc[0] + acc[1] + acc[2] + acc[3];
}

// ---------------- masked softmax for all steps (f32x4 loads) ---------------
__global__ void softmax_all_k(const float* __restrict__ part, const float* __restrict__ B480,
                              const int* __restrict__ rel_idx, u16* __restrict__ attn) {
  const int task = blockIdx.x * 4 + (threadIdx.x >> 6);
  const int lane = threadIdx.x & 63;
  const int tt = task >> 13;            // /NT
  const int i  = task & (NT - 1);
  const float* cur = part + (size_t)i * (TT * R) + (size_t)tt * R;
  const float* b = B480 + (size_t)rel_idx[i] * R;
  f32x4 v[2];
  float m = -3e38f;
  const bool act1 = lane < 56;
  #pragma unroll
  for (int jj = 0; jj < 2; ++jj) {
    const int r0 = jj * 256 + lane * 4;
    f32x4 val = {-1e9f, -1e9f, -1e9f, -1e9f};
    if (jj == 0 || act1) {
      const f32x4 c4 = *(const f32x4*)&cur[r0];
      const f32x4 b4 = *(const f32x4*)&b[r0];
      #pragma unroll
      for (int x = 0; x < 4; ++x) {
        val[x] = (c4[x] == 0.f) ? -1e9f : c4[x] * b4[x];
        m = fmaxf(m, val[x]);
      }
    }
    v[jj] = val;
  }
  #pragma unroll
  for (int o = 32; o; o >>= 1) m = fmaxf(m, __shfl_xor(m, o));
  float s = 0.f;
  #pragma unroll
  for (int jj = 0; jj < 2; ++jj) {
    if (jj == 0 || act1) {
      #pragma unroll
      for (int x = 0; x < 4; ++x) { v[jj][x] = __expf(v[jj][x] - m); s += v[jj][x]; }
    }
  }
  #pragma unroll
  for (int o = 32; o; o >>= 1) s += __shfl_xor(s, o);
  const float inv = 1.f / s;
  u16* arow = attn + (size_t)task * RP;
  #pragma unroll
  for (int jj = 0; jj < 2; ++jj) {
    const int r0 = jj * 256 + lane * 4;
    u16x4 o = {0, 0, 0, 0};
    if (jj == 0 || act1) {
      #pragma unroll
      for (int x = 0; x < 4; ++x) o[x] = f2b(v[jj][x] * inv);
    }
    *(u16x4*)&arow[r0] = o;
  }
}

// ---------------- single-launch 10-step scan -------------------------------
__launch_bounds__(256)
__global__ void scan_k(const u16* __restrict__ WhhT, const float* __restrict__ bhh,
                       const u16* __restrict__ gi_all, float* __restrict__ hbuf) {
  __shared__ __align__(16) u16 As[32 * 256];
  __shared__ __align__(16) u16 Bs[2][192 * 64];
  const int tid = threadIdx.x;
  const int lane = tid & 63;
  const int wv = tid >> 6;
  const int rf = wv >> 1;
  const int ch = wv & 1;
  const int fr = lane & 15;
  const int fq = lane >> 4;
  const int row_l = rf * 16 + fr;
  const int grow = blockIdx.x * 32 + row_l;
  const int sw = (fr & 7) * 8;

  auto stageB = [&](int buf, int cg, int k0) {
    #pragma unroll
    for (int it = 0; it < 6; ++it) {
      const int c = it * 256 + tid;
      const int vr = c >> 3, s = c & 7;
      const int vcol = ((vr >> 6) * 256) + cg * 64 + (vr & 63);
      gload_lds16(WhhT + (size_t)vcol * 256 + k0 + ((s ^ (vr & 7)) * 8),
                  &Bs[buf][(it * 256 + wv * 64) * 8]);
    }
  };

  float hreg[4][2][4];
  #pragma unroll
  for (int cg = 0; cg < 4; ++cg)
    #pragma unroll
    for (int nn = 0; nn < 2; ++nn)
      #pragma unroll
      for (int j = 0; j < 4; ++j) hreg[cg][nn][j] = 0.f;

  for (int t = 0; t < TT; ++t) {
    const u16* gi = gi_all + (size_t)t * NT * 768;
    #pragma unroll
    for (int cg = 0; cg < 4; ++cg) {
      f32x4 acc[6] = {};
      u16x4 gv[3][2];
      #pragma unroll
      for (int nn = 0; nn < 2; ++nn) {
        const int c = cg * 64 + ch * 32 + nn * 16 + fq * 4;
        const size_t gb = (size_t)grow * 768 + c;
        gv[0][nn] = *(const u16x4*)&gi[gb];
        gv[1][nn] = *(const u16x4*)&gi[gb + 256];
        gv[2][nn] = *(const u16x4*)&gi[gb + 512];
      }
      if (t > 0) {
        stageB(0, cg, 0);
        #pragma unroll
        for (int ki = 0; ki < 4; ++ki) {
          const int cb = ki & 1;
          if (ki < 3) {
            stageB(cb ^ 1, cg, (ki + 1) * 64);
            asm volatile("s_waitcnt vmcnt(6)" ::: "memory");
          } else {
            asm volatile("s_waitcnt vmcnt(0)" ::: "memory");
          }
          __builtin_amdgcn_sched_barrier(0);
          __builtin_amdgcn_s_barrier();
          #pragma unroll
          for (int kk = 0; kk < 2; ++kk) {
            const int ko = (ki * 64 + kk * 32 + fq * 8) ^ sw;
            const bf16x8 a = *(const bf16x8*)&As[row_l * 256 + ko];
            const int bo = (kk * 32 + fq * 8) ^ sw;
            #pragma unroll
            for (int g = 0; g < 3; ++g)
              #pragma unroll
              for (int nn = 0; nn < 2; ++nn) {
                const int vr = g * 64 + ch * 32 + nn * 16 + fr;
                const bf16x8 b = *(const bf16x8*)&Bs[cb][vr * 64 + bo];
                acc[g * 2 + nn] =
                    __builtin_amdgcn_mfma_f32_16x16x32_bf16(b, a, acc[g * 2 + nn], 0, 0, 0);
              }
          }
          __builtin_amdgcn_s_barrier();
        }
      }
      #pragma unroll
      for (int nn = 0; nn < 2; ++nn) {
        const int c = cg * 64 + ch * 32 + nn * 16 + fq * 4;
        const f32x4 bn = *(const f32x4*)&bhh[512 + c];
        #pragma unroll
        for (int j = 0; j < 4; ++j) {
          const float rg = 1.f / (1.f + __expf(-(b2f(gv[0][nn][j]) + acc[nn][j])));
          const float zg = 1.f / (1.f + __expf(-(b2f(gv[1][nn][j]) + acc[2 + nn][j])));
          const float ng = tanhf(b2f(gv[2][nn][j]) + rg * (acc[4 + nn][j] + bn[j]));
          hreg[cg][nn][j] = (1.f - zg) * ng + zg * hreg[cg][nn][j];
        }
      }
    }
    #pragma unroll
    for (int cg = 0; cg < 4; ++cg)
      #pragma unroll
      for (int nn = 0; nn < 2; ++nn) {
        const int c = cg * 64 + ch * 32 + nn * 16 + fq * 4;
        u16x4 o;
        #pragma unroll
        for (int j = 0; j < 4; ++j) o[j] = f2b(hreg[cg][nn][j]);
        *(u16x4*)&As[row_l * 256 + (c ^ sw)] = o;
        if (t == TT - 1) {
          f32x4 hv;
          #pragma unroll
          for (int j = 0; j < 4; ++j) hv[j] = hreg[cg][nn][j];
          *(f32x4*)&hbuf[(size_t)grow * 256 + c] = hv;
        }
      }
    __syncthreads();
  }
}

// ---------------- gathers / converts (vectorized) --------------------------
__global__ void gather_sub_k(const float* __restrict__ pre, const int* __restrict__ sub,
                             u16* __restrict__ sb) {
  const int q = blockIdx.x * 256 + threadIdx.x;
  const int i = q >> 6, c = (q & 63) * 4;
  const f32x4 v = *(const f32x4*)&pre[(size_t)sub[i] * H + c];
  u16x4 o;
  #pragma unroll
  for (int j = 0; j < 4; ++j) o[j] = f2b(v[j]);
  *(u16x4*)&sb[(size_t)q * 4] = o;
}
__global__ void cvt_pre_k(const float* __restrict__ pre, u16* __restrict__ pb) {
  const int q = blockIdx.x * 256 + threadIdx.x;
  const f32x4 v = *(const f32x4*)&pre[(size_t)q * 4];
  u16x4 o;
  #pragma unroll
  for (int j = 0; j < 4; ++j) o[j] = f2b(v[j]);
  *(u16x4*)&pb[(size_t)q * 4] = o;
}

// ---------------- final scalar reduction -----------------------------------
__global__ void finalize_k(const float* __restrict__ mp, const float* __restrict__ sp,
                           float* __restrict__ out) {
  const int tid = threadIdx.x;
  float s1 = 0.f, s2 = 0.f;
  for (int i = tid; i < 128; i += 256) s1 += mp[i];
  for (int i = tid; i < 3072; i += 256) s2 += sp[i];
  #pragma unroll
  for (int o = 32; o; o >>= 1) {
    s1 += __shfl_down(s1, o); s2 += __shfl_down(s2, o);
  }
  __shared__ float r1[4], r2[4];
  if ((tid & 63) == 0) { r1[tid >> 6] = s1; r2[tid >> 6] = s2; }
  __syncthreads();
  if (tid == 0) {
    const float a = r1[0] + r1[1] + r1[2] + r1[3];
    const float b = r2[0] + r2[1] + r2[2] + r2[3];
    out[0] = a / 2097152.f;
    out[1] = b / 188416000.f;
  }
}

// ---------------- 128-tile bf16 MFMA GEMM (MODE 0 / 2) ---------------------
template <int MODE>
__launch_bounds__(256)
__global__ void gemm_k(const u16* __restrict__ A, const u16* __restrict__ Bt,
                       const float* __restrict__ bias,
                       float* __restrict__ Cf, u16* __restrict__ Cb,
                       int M, int N, int K,
                       float* __restrict__ out2, float* __restrict__ part,
                       const int* __restrict__ idxv, const float* __restrict__ Pf,
                       const float* __restrict__ G2f, const float* __restrict__ hf) {
  __shared__ __align__(16) u16 As[128 * 64];
  __shared__ __align__(16) u16 Bs[128 * 64];
  __shared__ float red[4];
  const int tid = threadIdx.x;
  const int lane = tid & 63;
  const int wv = tid >> 6;
  const int nbx = gridDim.x;
  int flat = blockIdx.y * nbx + blockIdx.x;
  const int nwg = nbx * gridDim.y;
  if ((nwg & 7) == 0) flat = (flat & 7) * (nwg >> 3) + (flat >> 3);
  const int bx = flat % nbx;
  const int by = flat / nbx;
  const int m0 = by * 128;
  const int n0 = bx * 128;
  const int wm = (wv >> 1) * 64;
  const int wn = (wv & 1) * 64;
  const int fr = lane & 15;
  const int fq = lane >> 4;
  const int sw = (lane & 7) * 8;
  f32x4 acc[4][4] = {};

  const int nsteps = K >> 6;
  for (int kt = 0; kt < nsteps; ++kt) {
    const int k0 = kt * 64;
    if (kt > 0) __syncthreads();
    #pragma unroll
    for (int it = 0; it < 4; ++it) {
      const int c = it * 256 + tid;
      const int row = c >> 3, s = c & 7;
      const int sc = (s ^ (row & 7)) * 8;
      int gr = m0 + row; gr = gr < M ? gr : M - 1;
      gload_lds16(A + (size_t)gr * K + k0 + sc, &As[(it * 256 + wv * 64) * 8]);
      int nr = n0 + row; nr = nr < N ? nr : N - 1;
      gload_lds16(Bt + (size_t)nr * K + k0 + sc, &Bs[(it * 256 + wv * 64) * 8]);
    }
    asm volatile("s_waitcnt vmcnt(0)" ::: "memory");
    __builtin_amdgcn_sched_barrier(0);
    __builtin_amdgcn_s_barrier();
    #pragma unroll
    for (int kk = 0; kk < 2; ++kk) {
      const int ko = (kk * 32 + fq * 8) ^ sw;
      bf16x8 a[4], b[4];
      #pragma unroll
      for (int mi = 0; mi < 4; ++mi)
        a[mi] = *(const bf16x8*)&As[(wm + mi * 16 + fr) * 64 + ko];
      #pragma unroll
      for (int ni = 0; ni < 4; ++ni)
        b[ni] = *(const bf16x8*)&Bs[(wn + ni * 16 + fr) * 64 + ko];
      #pragma unroll
      for (int mi = 0; mi < 4; ++mi)
        #pragma unroll
        for (int ni = 0; ni < 4; ++ni)
          acc[mi][ni] = __builtin_amdgcn_mfma_f32_16x16x32_bf16(b[ni], a[mi], acc[mi][ni], 0, 0, 0);
    }
  }

  float local = 0.f;
  #pragma unroll
  for (int mi = 0; mi < 4; ++mi) {
    const int rowm = m0 + wm + mi * 16 + fr;
    int iv = 0;
    if (MODE == 2) iv = idxv[rowm < M ? rowm : M - 1];
    #pragma unroll
    for (int ni = 0; ni < 4; ++ni) {
      const int col = n0 + wn + ni * 16 + fq * 4;
      if (rowm < M && col < N) {
        f32x4 v = acc[mi][ni];
        if (MODE == 0) {
          if (bias != nullptr) {
            const f32x4 bv = *(const f32x4*)&bias[col];
            #pragma unroll
            for (int j = 0; j < 4; ++j) v[j] += bv[j];
          }
          if (Cf) *(f32x4*)&Cf[(size_t)rowm * N + col] = v;
          if (Cb) {
            u16x4 o;
            #pragma unroll
            for (int j = 0; j < 4; ++j) o[j] = f2b(v[j]);
            *(u16x4*)&Cb[(size_t)rowm * N + col] = o;
          }
        } else {
          const f32x4 bv = *(const f32x4*)&bias[col];
          const f32x4 Pv = *(const f32x4*)&Pf[(size_t)iv * H + col];
          const f32x4 Gv = *(const f32x4*)&G2f[(size_t)iv * H + col];
          const f32x4 hv = *(const f32x4*)&hf[(size_t)rowm * H + col];
          u16x4 o;
          #pragma unroll
          for (int j = 0; j < 4; ++j) {
            const float d = Pv[j] - hv[j];
            local += d * d;
            o[j] = f2b((v[j] + bv[j]) * Gv[j]);
          }
          *(u16x4*)&Cb[(size_t)rowm * N + col] = o;
        }
      }
    }
  }
  if (MODE == 2) {
    #pragma unroll
    for (int o = 32; o; o >>= 1) local += __shfl_down(local, o);
    if (lane == 0) red[wv] = local;
    __syncthreads();
    if (tid == 0) part[blockIdx.y * gridDim.x + blockIdx.x] = red[0] + red[1] + red[2] + red[3];
  }
}

// ---------------- 256-tile bf16 MFMA GEMM, BK=64 single-buffer -------------
// MODE 0: Cb = bf16(A@B + bias)   (gi GEMM; old %8 swizzle)
// MODE 1: sigmoid -> out2 (normal stores; L2 merges the +8B-offset runs),
//   (softplus - pos) partials -> part. XCD-column-affine mapping: grid
//   (96,32); xcd = flat&7 owns a 12-wide column slice -> alT slice 1.57 MB
//   is per-XCD-L2 resident (R13 measured FETCH 194->22.5 MB). Idle blocks
//   (bx>=90) zero their part slot and exit before any barrier.
template <int MODE>
__launch_bounds__(512)
__global__ void gemm256_k(const u16* __restrict__ A, const u16* __restrict__ Bt,
                          const float* __restrict__ bias, u16* __restrict__ Cb,
                          int M, int N, int K,
                          float* __restrict__ out2, float* __restrict__ part,
                          const int* __restrict__ idxv) {
  __shared__ __align__(16) u16 As[256 * 64];
  __shared__ __align__(16) u16 Bs[256 * 64];
  __shared__ float red[8];
  const int tid = threadIdx.x;
  const int lane = tid & 63;
  const int wv = tid >> 6;
  int bx, by, pslot;
  if (MODE == 1) {
    const int flat = blockIdx.y * 96 + blockIdx.x;   // gridDim.x == 96
    pslot = flat;
    const int xcd = flat & 7;
    const int i = flat >> 3;                          // 0..383
    bx = xcd * 12 + (i % 12);
    by = i / 12;                                      // 0..31
    if (bx >= 90) {                                   // 23040-col pad region
      if (tid == 0) part[pslot] = 0.f;
      return;
    }
  } else {
    const int nbx = gridDim.x;
    int flat = blockIdx.y * nbx + blockIdx.x;
    const int nwg = nbx * gridDim.y;
    if ((nwg & 7) == 0) flat = (flat & 7) * (nwg >> 3) + (flat >> 3);
    bx = flat % nbx;
    by = flat / nbx;
    pslot = 0;
  }
  const int m0 = by * 256;
  const int n0 = bx * 256;
  const int wm = (wv >> 2) * 128;      // 2 M-groups of 128
  const int wn = (wv & 3) * 64;        // 4 N-groups of 64
  const int fr = lane & 15;
  const int fq = lane >> 4;
  const int sw = (lane & 7) * 8;
  f32x4 acc[8][4] = {};

  const int nsteps = K >> 6;
  for (int kt = 0; kt < nsteps; ++kt) {
    const int k0 = kt * 64;
    if (kt > 0) __syncthreads();        // WAR: all waves done reading LDS
    #pragma unroll
    for (int it = 0; it < 4; ++it) {
      const int c = it * 512 + tid;     // 2048 16B chunks per matrix
      const int row = c >> 3, s = c & 7;
      const int sc = (s ^ (row & 7)) * 8;
      int gr = m0 + row; gr = gr < M ? gr : M - 1;
      gload_lds16(A + (size_t)gr * K + k0 + sc, &As[(it * 512 + wv * 64) * 8]);
      int nr = n0 + row; nr = nr < N ? nr : N - 1;
      gload_lds16(Bt + (size_t)nr * K + k0 + sc, &Bs[(it * 512 + wv * 64) * 8]);
    }
    asm volatile("s_waitcnt vmcnt(0)" ::: "memory");
    __builtin_amdgcn_sched_barrier(0);
    __builtin_amdgcn_s_barrier();
    #pragma unroll
    for (int kk = 0; kk < 2; ++kk) {
      const int ko = (kk * 32 + fq * 8) ^ sw;
      bf16x8 a[8], b[4];
      #pragma unroll
      for (int mi = 0; mi < 8; ++mi)
        a[mi] = *(const bf16x8*)&As[(wm + mi * 16 + fr) * 64 + ko];
      #pragma unroll
      for (int ni = 0; ni < 4; ++ni)
        b[ni] = *(const bf16x8*)&Bs[(wn + ni * 16 + fr) * 64 + ko];
      #pragma unroll
      for (int mi = 0; mi < 8; ++mi)
        #pragma unroll
        for (int ni = 0; ni < 4; ++ni)
          acc[mi][ni] = __builtin_amdgcn_mfma_f32_16x16x32_bf16(b[ni], a[mi], acc[mi][ni], 0, 0, 0);
    }
  }

  float local = 0.f;
  #pragma unroll
  for (int mi = 0; mi < 8; ++mi) {
    const int rowm = m0 + wm + mi * 16 + fr;
    int iv = 0;
    if (MODE == 1) iv = idxv[rowm < M ? rowm : M - 1];
    #pragma unroll
    for (int ni = 0; ni < 4; ++ni) {
      const int col = n0 + wn + ni * 16 + fq * 4;
      if (rowm < M && col < N) {
        const f32x4 v = acc[mi][ni];
        if (MODE == 0) {
          const f32x4 bv = *(const f32x4*)&bias[col];
          u16x4 o;
          #pragma unroll
          for (int j = 0; j < 4; ++j) o[j] = f2b(v[j] + bv[j]);
          *(u16x4*)&Cb[(size_t)rowm * N + col] = o;
        } else {
          f32x4 sg;
          #pragma unroll
          for (int j = 0; j < 4; ++j) {
            const float s = v[j];
            const float sig = 1.f / (1.f + __expf(-s));
            sg[j] = sig;
            const float om = 1.f - sig;
            local += (om > 0.f) ? -__logf(om) : s;     // softplus(s)
            if (col + j == iv) local -= s;             // pos fold
          }
          *(f32x4*)&out2[(size_t)rowm * N + col] = sg;
        }
      }
    }
  }
  if (MODE == 1) {
    #pragma unroll
    for (int o = 32; o; o >>= 1) local += __shfl_down(local, o);
    if (lane == 0) red[wv] = local;
    __syncthreads();
    if (tid == 0) {
      float s = 0.f;
      #pragma unroll
      for (int x = 0; x < 8; ++x) s += red[x];
      part[pslot] = s;
    }
  }
}

extern "C" void kernel_launch(void* const* d_in, const int* in_sizes, int n_in,
                              void* d_out, int out_size, void* d_ws, size_t ws_size,
                              hipStream_t stream) {
  const float* pre_emb = (const float*)d_in[0];
  const float* r_emb   = (const float*)d_in[1];
  const float* part_e  = (const float*)d_in[2];
  const int*   sub_idx = (const int*)d_in[3];
  const int*   rel_idx = (const int*)d_in[4];
  const int*   obj_idx = (const int*)d_in[5];
  const float* Wm1 = (const float*)d_in[7];  const float* bm1 = (const float*)d_in[8];
  const float* Wm2 = (const float*)d_in[9];  const float* bm2 = (const float*)d_in[10];
  const float* Wattn = (const float*)d_in[11]; const float* battn = (const float*)d_in[12];
  const float* Wh1 = (const float*)d_in[13]; const float* bh1 = (const float*)d_in[14];
  const float* Wh2 = (const float*)d_in[15]; const float* bh2 = (const float*)d_in[16];
  const float* Walign = (const float*)d_in[17]; const float* balign = (const float*)d_in[18];
  const float* Wih = (const float*)d_in[19]; const float* Whh = (const float*)d_in[20];
  const float* bih = (const float*)d_in[21]; const float* bhh = (const float*)d_in[22];
  float* out = (float*)d_out;

  char* w = (char*)d_ws;
  size_t off = 0;
  auto alloc = [&](size_t bytes) -> void* {
    off = (off + 255) & ~(size_t)255;
    void* p = w + off;
    off += bytes;
    return p;
  };
  float* mapped = (float*)alloc((size_t)R * H * 4);
  float* t1     = (float*)alloc((size_t)R * H * 4);
  float* B480   = (float*)alloc((size_t)R * R * 4);
  float* P      = (float*)alloc((size_t)R * H * 4);
  float* G2     = (float*)alloc((size_t)R * H * 4);
  u16* MWT      = (u16*)alloc((size_t)768 * RP * 2);
  u16* WhhT     = (u16*)alloc((size_t)768 * H * 2);
  u16* WalignT  = (u16*)alloc((size_t)H * H * 2);
  float* bsum   = (float*)alloc(768 * 4);
  float* hbuf   = (float*)alloc((size_t)NT * H * 4);
  u16* lhs_b    = (u16*)alloc((size_t)NT * H * 2);
  u16* sub_b    = (u16*)alloc((size_t)NT * H * 2);
  u16* pre_b    = (u16*)alloc((size_t)NE * H * 2);
  u16* alT      = (u16*)alloc((size_t)NE * H * 2);
  float* mpart  = (float*)alloc(128 * 4);
  float* spart  = (float*)alloc(3072 * 4);
  u16* attn_all = (u16*)alloc((size_t)TT * NT * RP * 2);
  u16* gi_all   = (u16*)alloc((size_t)TT * NT * 768 * 2);
  if (off > ws_size) return;  // workspace insufficient; fail visibly

  // rank-480 precompute + weight prep + MWT pad (one launch)
  stageA_k<<<480 + 1030, 256, 0, stream>>>(
      r_emb, Wm1, bm1, Wm2, bm2, Wattn, battn, Wih, Wh1, bh1, Wh2, bh2,
      Whh, bhh, bih, Walign, mapped, t1, P, G2, MWT, WhhT, WalignT, bsum);
  sgemm_bt_k<<<(R * R + 255) / 256, 256, 0, stream>>>(t1, mapped, B480, R, R, H);

  // all-step softmax + batched gi GEMM (256-tile) + single-launch scan
  softmax_all_k<<<TT * (NT / 4), 256, 0, stream>>>(part_e, B480, rel_idx, attn_all);
  gemm256_k<0><<<dim3(3, TT * (NT / 256)), 512, 0, stream>>>(
      attn_all, MWT, bsum, gi_all, TT * NT, 768, RP, nullptr, nullptr, nullptr);
  scan_k<<<NT / 32, 256, 0, stream>>>(WhhT, bhh, gi_all, hbuf);

  // sub gather + fused (asub GEMM + lhs + match partials)
  gather_sub_k<<<NT / 4, 256, 0, stream>>>(pre_emb, sub_idx, sub_b);
  gemm_k<2><<<dim3(2, 64), 256, 0, stream>>>(
      sub_b, WalignT, balign, nullptr, lhs_b, NT, H, H,
      nullptr, mpart, rel_idx, P, G2, hbuf);

  // aligned entity table
  cvt_pre_k<<<NE / 4, 256, 0, stream>>>(pre_emb, pre_b);
  gemm_k<0><<<dim3(2, 180), 256, 0, stream>>>(
      pre_b, WalignT, balign, nullptr, alT, NE, H, H,
      nullptr, nullptr, nullptr, nullptr, nullptr, nullptr);

  // final score GEMM: XCD-column-affine grid (96,32), normal stores
  gemm256_k<1><<<dim3(96, 32), 512, 0, stream>>>(
      lhs_b, alT, nullptr, nullptr, NT, NE, H, out + 2, spart, obj_idx);

  // final scalars
  finalize_k<<<1, 256, 0, stream>>>(mpart, spart, out);
}